// Round 7
// baseline (2630.483 us; speedup 1.0000x reference)
//
#include <hip/hip_runtime.h>
#include <stdint.h>

// IntegratedNCA: 64 NCA steps. B=8, CH=16, H=W=96, HID=128, WDIM=128.
// Multi-launch (per-step kernel = the global sync). Phase B (life masking)
// fused into the NEXT step's staging: X_s = Y_{s-1} * life_{s-1} in LDS.
//
// R7: 8x8 tile x hidden-split-8 (512 thr, wave = 16 hidden units), 1152 blocks
// -> 32 waves/CU resident (was 18). In-place LDS reduction, 3 barriers.
//
// PRNG: JAX threefry, jax_threefry_partitionable=True (green R2/R5/R6):
//   split: key[i]  = threefry2x32(0,42, 0, i)   (host-side, passed as args)
//   bits : bits[p] = o0^o1, (o0,o1)=threefry2x32(key, 0, p); uniform<0.5 <=> bits>>31==0

#define CHN 16
#define HIDN 128
#define WD 128
#define NB 8
#define NH 96
#define NW 96
#define NSTEPS 64
#define TW 8
#define TH 8
#define PLANE (NH*NW)          // 9216
#define TILES_X (NW/TW)        // 12
#define TILES_Y (NH/TH)        // 12
#define TPI (TILES_X*TILES_Y)  // 144
#define NBLK (NB*TPI)          // 1152
#define HW_ (TH+2)             // 10 staged rows (halo 1)
#define WW_ (TW+2)             // 10 staged cols (halo 1)
#define NT 512                 // threads per step-block

__host__ __device__ __forceinline__ uint32_t rotl(uint32_t v, int d){ return (v<<d)|(v>>(32-d)); }

__host__ __device__ __forceinline__ void threefry2x32(uint32_t k0, uint32_t k1,
                                                      uint32_t x0, uint32_t x1,
                                                      uint32_t &o0, uint32_t &o1){
  uint32_t k2 = k0 ^ k1 ^ 0x1BD11BDAu;
  x0 += k0; x1 += k1;
  x0 += x1; x1 = rotl(x1,13); x1 ^= x0;
  x0 += x1; x1 = rotl(x1,15); x1 ^= x0;
  x0 += x1; x1 = rotl(x1,26); x1 ^= x0;
  x0 += x1; x1 = rotl(x1, 6); x1 ^= x0;
  x0 += k1; x1 += k2 + 1u;
  x0 += x1; x1 = rotl(x1,17); x1 ^= x0;
  x0 += x1; x1 = rotl(x1,29); x1 ^= x0;
  x0 += x1; x1 = rotl(x1,16); x1 ^= x0;
  x0 += x1; x1 = rotl(x1,24); x1 ^= x0;
  x0 += k2; x1 += k0 + 2u;
  x0 += x1; x1 = rotl(x1,13); x1 ^= x0;
  x0 += x1; x1 = rotl(x1,15); x1 ^= x0;
  x0 += x1; x1 = rotl(x1,26); x1 ^= x0;
  x0 += x1; x1 = rotl(x1, 6); x1 ^= x0;
  x0 += k0; x1 += k1 + 3u;
  x0 += x1; x1 = rotl(x1,17); x1 ^= x0;
  x0 += x1; x1 = rotl(x1,29); x1 ^= x0;
  x0 += x1; x1 = rotl(x1,16); x1 ^= x0;
  x0 += x1; x1 = rotl(x1,24); x1 ^= x0;
  x0 += k1; x1 += k2 + 4u;
  x0 += x1; x1 = rotl(x1,13); x1 ^= x0;
  x0 += x1; x1 = rotl(x1,15); x1 ^= x0;
  x0 += x1; x1 = rotl(x1,26); x1 ^= x0;
  x0 += x1; x1 = rotl(x1, 6); x1 ^= x0;
  x0 += k2; x1 += k0 + 5u;
  o0 = x0; o1 = x1;
}

// Pre: w1eff[128][32] (cols 0..15 = W1[:, :16]; 16..31 folded perception pairs),
// w2t[128][16] = W2^T, c1[8][128] = b1 + W1[:,48:176].w[b].
__global__ __launch_bounds__(256) void nca_pre(
    const float* __restrict__ w, const float* __restrict__ W1,
    const float* __restrict__ b1, const float* __restrict__ W2,
    float* __restrict__ w1eff, float* __restrict__ w2t, float* __restrict__ c1)
{
  const int b = blockIdx.x, t = threadIdx.x;
  if (b == 0){
    for (int idx = t; idx < HIDN*32; idx += 256){
      int n = idx >> 5, k = idx & 31;
      float v;
      if (k < 16) v = W1[n*176 + k];
      else { int cc = k - 16; v = W1[n*176 + 16 + 2*cc] + W1[n*176 + 17 + 2*cc]; }
      w1eff[idx] = v;
    }
    for (int idx = t; idx < HIDN*CHN; idx += 256){
      int n = idx >> 4, cc = idx & 15;
      w2t[idx] = W2[cc*HIDN + n];
    }
  }
  if (t < HIDN){
    float s = b1[t];
    const float* wrow = W1 + t*176 + 48;
    const float* wb = w + b*WD;
    #pragma unroll 8
    for (int k = 0; k < WD; ++k) s = fmaf(wrow[k], wb[k], s);
    c1[b*HIDN + t] = s;
  }
}

// One NCA step. Block = 8x8 pixel tile x 8 hidden eighths (512 thr, q=wave).
// FIRST: X = input x. Else: X = Yp * (Mp & living(Yp alpha)) built in LDS.
template<bool FIRST>
__global__ __launch_bounds__(NT, 8) void nca_step(
    const float* __restrict__ Xin,          // x if FIRST, else Y_{s-1}
    const unsigned char* __restrict__ Mp,   // M_{s-1} (ignored if FIRST)
    const float* __restrict__ w1eff, const float* __restrict__ w2t,
    const float* __restrict__ c1,
    uint32_t key0, uint32_t key1,
    float* __restrict__ Yn, unsigned char* __restrict__ Mn)
{
  __shared__ float xs[CHN][HW_][WW_];   //  6400 B: X tile + halo 1
  __shared__ float ya[HW_+2][WW_+2];    //   576 B: Y alpha + halo 2
  __shared__ float lifes[HW_][WW_];     //   400 B
  __shared__ float red[4][CHN][64];     // 16384 B: reduction, lane=px -> 2-way (free)

  const int T = blockIdx.x;
  const int b = T / TPI, t = T % TPI;
  const int tw0 = (t % TILES_X)*TW, th0 = (t / TILES_X)*TH;
  const int tid = threadIdx.x;

  if (FIRST){
    for (int idx = tid; idx < CHN*HW_*WW_; idx += NT){
      int ch = idx / (HW_*WW_), rem = idx % (HW_*WW_);
      int hh = rem / WW_, ww = rem % WW_;
      int g2 = th0 - 1 + hh, w2 = tw0 - 1 + ww;
      float v = 0.f;
      if ((unsigned)g2 < NH && (unsigned)w2 < NW)
        v = Xin[((b*CHN + ch)*NH + g2)*NW + w2];
      xs[ch][hh][ww] = v;
    }
  } else {
    // Y alpha with halo 2 (zero-pad OOB: 0 <= 0.1 never flips the mask)
    for (int idx = tid; idx < (HW_+2)*(WW_+2); idx += NT){
      int hh = idx / (WW_+2), ww = idx % (WW_+2);
      int g2 = th0 - 2 + hh, w2 = tw0 - 2 + ww;
      float v = 0.f;
      if ((unsigned)g2 < NH && (unsigned)w2 < NW)
        v = Xin[((b*CHN + 3)*NH + g2)*NW + w2];
      ya[hh][ww] = v;
    }
    __syncthreads();
    // life over tile + halo 1
    for (int idx = tid; idx < HW_*WW_; idx += NT){
      int hh = idx / WW_, ww = idx % WW_;
      int g2 = th0 - 1 + hh, w2 = tw0 - 1 + ww;
      float lf = 0.f;
      if ((unsigned)g2 < NH && (unsigned)w2 < NW){
        float mx = ya[hh][ww];
        #pragma unroll
        for (int dr = 0; dr < 3; ++dr)
          #pragma unroll
          for (int dc = 0; dc < 3; ++dc)
            mx = fmaxf(mx, ya[hh+dr][ww+dc]);
        lf = (Mp[b*PLANE + g2*NW + w2] && (mx > 0.1f)) ? 1.f : 0.f;
      }
      lifes[hh][ww] = lf;
    }
    __syncthreads();
    // X = Y * life
    for (int idx = tid; idx < CHN*HW_*WW_; idx += NT){
      int ch = idx / (HW_*WW_), rem = idx % (HW_*WW_);
      int hh = rem / WW_, ww = rem % WW_;
      int g2 = th0 - 1 + hh, w2 = tw0 - 1 + ww;
      float v = 0.f;
      if ((unsigned)g2 < NH && (unsigned)w2 < NW)
        v = Xin[((b*CHN + ch)*NH + g2)*NW + w2] * lifes[hh][ww];
      xs[ch][hh][ww] = v;
    }
  }
  __syncthreads();

  const int px = tid & 63;          // pixel in 8x8 tile
  const int q  = tid >> 6;          // hidden eighth == wave id (0..7)
  const int c = px & 7, r = px >> 3;
  const int gh = th0 + r, gw = tw0 + c;
  const int pos = b*PLANE + gh*NW + gw;

  float xc[CHN], pc[CHN];
  #pragma unroll
  for (int ch = 0; ch < CHN; ++ch) xc[ch] = xs[ch][r+1][c+1];
  // grouped conv: out ch 0..7 -> sx, 8..15 -> sy (cross-correlation)
  #pragma unroll
  for (int ch = 0; ch < 8; ++ch){
    pc[ch] =      (xs[ch][r  ][c+2] - xs[ch][r  ][c  ])
           + 2.f*(xs[ch][r+1][c+2] - xs[ch][r+1][c  ])
           +     (xs[ch][r+2][c+2] - xs[ch][r+2][c  ]);
  }
  #pragma unroll
  for (int ch = 8; ch < 16; ++ch){
    pc[ch] =      (xs[ch][r+2][c  ] - xs[ch][r  ][c  ])
           + 2.f*(xs[ch][r+2][c+1] - xs[ch][r  ][c+1])
           +     (xs[ch][r+2][c+2] - xs[ch][r  ][c+2]);
  }

  float acc[CHN];
  #pragma unroll
  for (int i = 0; i < CHN; ++i) acc[i] = 0.f;
  // q is wave-uniform; readfirstlane keeps weight addresses provably scalar
  // (s_load path; SGPR=112 in green R5/R6 kernels).
  const int nbase = __builtin_amdgcn_readfirstlane(q) << 4;
  const float* c1b = c1 + b*HIDN;

  #pragma unroll 4
  for (int nn = 0; nn < 16; ++nn){
    const int n = nbase + nn;
    const float* wr = w1eff + (n << 5);
    float h0 = c1b[n], h1 = 0.f, h2 = 0.f, h3 = 0.f;
    #pragma unroll
    for (int k = 0; k < 8; ++k){
      h0 = fmaf(xc[k],   wr[k],    h0);
      h1 = fmaf(xc[k+8], wr[k+8],  h1);
      h2 = fmaf(pc[k],   wr[k+16], h2);
      h3 = fmaf(pc[k+8], wr[k+24], h3);
    }
    float hv = fmaxf((h0+h1)+(h2+h3), 0.f);
    const float* w2r = w2t + (n << 4);
    #pragma unroll
    for (int cc = 0; cc < CHN; ++cc) acc[cc] = fmaf(hv, w2r[cc], acc[cc]);
  }

  // ---- reduction: 8 partials -> 4 (pairwise) -> transpose via red -> 4-ch writes
  if (q >= 4){
    #pragma unroll
    for (int cc = 0; cc < CHN; ++cc) red[q-4][cc][px] = acc[cc];
  }
  __syncthreads();
  if (q < 4){
    #pragma unroll
    for (int cc = 0; cc < CHN; ++cc) acc[cc] += red[q][cc][px];
  }
  __syncthreads();
  if (q < 4){
    #pragma unroll
    for (int cc = 0; cc < CHN; ++cc) red[q][cc][px] = acc[cc];
  }
  __syncthreads();
  if (q < 4){
    uint32_t o0, o1;
    threefry2x32(key0, key1, 0u, (uint32_t)pos, o0, o1);
    float uf = ((((o0 ^ o1) >> 31) == 0u) && (xc[3] > 0.1f)) ? 1.f : 0.f;
    #pragma unroll
    for (int cc = 0; cc < 4; ++cc){
      int ch = (q << 2) + cc;
      float v = ((red[0][ch][px] + red[1][ch][px]) +
                 (red[2][ch][px] + red[3][ch][px]));
      Yn[((b*CHN + ch)*NH + gh)*NW + gw] = fmaf(v, uf, xc[ch]);
    }
  }
  if (q == 0){  // wave-uniform branch; pre_life from OLD X alpha
    float mx = xs[3][r][c];
    #pragma unroll
    for (int dr = 0; dr < 3; ++dr)
      #pragma unroll
      for (int dc = 0; dc < 3; ++dc)
        mx = fmaxf(mx, xs[3][r+dr][c+dc]);
    Mn[pos] = (mx > 0.1f) ? (unsigned char)1 : (unsigned char)0;
  }
}

// Final: out = Y_63 * (M_63 & living(Y_63 alpha))
__global__ __launch_bounds__(256) void nca_final(
    const float* __restrict__ Yp, const unsigned char* __restrict__ Mp,
    float* __restrict__ out)
{
  __shared__ float ya[HW_+2][WW_+2];
  __shared__ float lifes[TH][TW];
  const int T = blockIdx.x;
  const int b = T / TPI, t = T % TPI;
  const int tw0 = (t % TILES_X)*TW, th0 = (t / TILES_X)*TH;
  const int tid = threadIdx.x;
  for (int idx = tid; idx < (HW_+2)*(WW_+2); idx += 256){
    int hh = idx / (WW_+2), ww = idx % (WW_+2);
    int g2 = th0 - 2 + hh, w2 = tw0 - 2 + ww;
    float v = 0.f;
    if ((unsigned)g2 < NH && (unsigned)w2 < NW)
      v = Yp[((b*CHN + 3)*NH + g2)*NW + w2];
    ya[hh][ww] = v;
  }
  __syncthreads();
  if (tid < TH*TW){
    int i = tid >> 3, j = tid & 7;
    float mx = ya[i+1][j+1];
    #pragma unroll
    for (int dr = 0; dr < 3; ++dr)
      #pragma unroll
      for (int dc = 0; dc < 3; ++dc)
        mx = fmaxf(mx, ya[i+1+dr][j+1+dc]);
    lifes[i][j] = (Mp[b*PLANE + (th0+i)*NW + (tw0+j)] && (mx > 0.1f)) ? 1.f : 0.f;
  }
  __syncthreads();
  for (int idx = tid; idx < CHN*TH*TW; idx += 256){
    int ch = idx >> 6, p = idx & 63;
    int i = p >> 3, j = p & 7;
    int o = ((b*CHN + ch)*NH + th0 + i)*NW + tw0 + j;
    out[o] = Yp[o] * lifes[i][j];
  }
}

extern "C" void kernel_launch(void* const* d_in, const int* in_sizes, int n_in,
                              void* d_out, int out_size, void* d_ws, size_t ws_size,
                              hipStream_t stream) {
  const float* x  = (const float*)d_in[0];
  const float* w  = (const float*)d_in[1];
  // d_in[2] = sobel (hard-coded), d_in[6] = steps (=64, hard-coded)
  const float* W1 = (const float*)d_in[3];
  const float* b1 = (const float*)d_in[4];
  const float* W2 = (const float*)d_in[5];
  float* out = (float*)d_out;
  char* ws = (char*)d_ws;

  size_t off = 0;
  float*    w1eff = (float*)(ws + off);    off += (size_t)HIDN*32*4;
  float*    w2t   = (float*)(ws + off);    off += (size_t)HIDN*CHN*4;
  float*    c1    = (float*)(ws + off);    off += (size_t)NB*HIDN*4;
  float*    Yb0   = (float*)(ws + off);    off += (size_t)NB*CHN*PLANE*4;
  float*    Yb1   = (float*)(ws + off);    off += (size_t)NB*CHN*PLANE*4;
  unsigned char* Mb0 = (unsigned char*)(ws + off); off += (size_t)NB*PLANE;
  unsigned char* Mb1 = (unsigned char*)(ws + off); off += (size_t)NB*PLANE;
  (void)ws_size; (void)in_sizes; (void)n_in; (void)out_size;

  // step keys are input-independent constants: compute on host, pass as args
  uint32_t k0[NSTEPS], k1[NSTEPS];
  for (int s = 0; s < NSTEPS; ++s) threefry2x32(0u, 42u, 0u, (uint32_t)s, k0[s], k1[s]);

  nca_pre<<<dim3(NB), dim3(256), 0, stream>>>(w, W1, b1, W2, w1eff, w2t, c1);

  nca_step<true><<<dim3(NBLK), dim3(NT), 0, stream>>>(
      x, Mb1 /*unused*/, w1eff, w2t, c1, k0[0], k1[0], Yb0, Mb0);
  for (int s = 1; s < NSTEPS; ++s){
    const float* Yp = (s & 1) ? Yb0 : Yb1;
    float*       Yn = (s & 1) ? Yb1 : Yb0;
    const unsigned char* Mq = (s & 1) ? Mb0 : Mb1;
    unsigned char*       Mn = (s & 1) ? Mb1 : Mb0;
    nca_step<false><<<dim3(NBLK), dim3(NT), 0, stream>>>(
        Yp, Mq, w1eff, w2t, c1, k0[s], k1[s], Yn, Mn);
  }
  // s=63 (odd) wrote Yb1/Mb1
  nca_final<<<dim3(NBLK), dim3(256), 0, stream>>>(Yb1, Mb1, out);
}

// Round 8
// 1533.712 us; speedup vs baseline: 1.7151x; 1.7151x over previous
//
#include <hip/hip_runtime.h>
#include <stdint.h>

// IntegratedNCA: 64 NCA steps. B=8, CH=16, H=W=96, HID=128, WDIM=128.
// Multi-launch (per-step kernel = the global sync). Phase B (life masking)
// fused into the NEXT step's staging: X_s = Y_{s-1} * life_{s-1} in LDS.
//
// R8: 16x4 pixel tile (64 px) x hidden-split-4 (256 thr, wave = 32 hidden
// units; R6's proven MLP core). 16-wide rows -> 64B-aligned global segments
// (R7's 8-wide tiles caused 3-10x FETCH/WRITE amplification). Block index =
// tile*8 + image: dispatch round-robins XCDs %8, pinning each image (590 KB)
// to one XCD's L2 across steps. Y read once per step (register staging).
//
// PRNG: JAX threefry, jax_threefry_partitionable=True (green R2/R5/R6):
//   split: key[i]  = threefry2x32(0,42, 0, i)   (host-side, passed as args)
//   bits : bits[p] = o0^o1, (o0,o1)=threefry2x32(key, 0, p); uniform<0.5 <=> bits>>31==0

#define CHN 16
#define HIDN 128
#define WD 128
#define NB 8
#define NH 96
#define NW 96
#define NSTEPS 64
#define TW 16
#define TH 4
#define PLANE (NH*NW)          // 9216
#define TILES_X (NW/TW)        // 6
#define TILES_Y (NH/TH)        // 24
#define TPI (TILES_X*TILES_Y)  // 144
#define NBLK (NB*TPI)          // 1152
#define HW_ (TH+2)             // 6 staged rows (halo 1)
#define WW_ (TW+2)             // 18 staged cols (halo 1)
#define XS_N (CHN*HW_*WW_)     // 1728 staged X elements

__host__ __device__ __forceinline__ uint32_t rotl(uint32_t v, int d){ return (v<<d)|(v>>(32-d)); }

__host__ __device__ __forceinline__ void threefry2x32(uint32_t k0, uint32_t k1,
                                                      uint32_t x0, uint32_t x1,
                                                      uint32_t &o0, uint32_t &o1){
  uint32_t k2 = k0 ^ k1 ^ 0x1BD11BDAu;
  x0 += k0; x1 += k1;
  x0 += x1; x1 = rotl(x1,13); x1 ^= x0;
  x0 += x1; x1 = rotl(x1,15); x1 ^= x0;
  x0 += x1; x1 = rotl(x1,26); x1 ^= x0;
  x0 += x1; x1 = rotl(x1, 6); x1 ^= x0;
  x0 += k1; x1 += k2 + 1u;
  x0 += x1; x1 = rotl(x1,17); x1 ^= x0;
  x0 += x1; x1 = rotl(x1,29); x1 ^= x0;
  x0 += x1; x1 = rotl(x1,16); x1 ^= x0;
  x0 += x1; x1 = rotl(x1,24); x1 ^= x0;
  x0 += k2; x1 += k0 + 2u;
  x0 += x1; x1 = rotl(x1,13); x1 ^= x0;
  x0 += x1; x1 = rotl(x1,15); x1 ^= x0;
  x0 += x1; x1 = rotl(x1,26); x1 ^= x0;
  x0 += x1; x1 = rotl(x1, 6); x1 ^= x0;
  x0 += k0; x1 += k1 + 3u;
  x0 += x1; x1 = rotl(x1,17); x1 ^= x0;
  x0 += x1; x1 = rotl(x1,29); x1 ^= x0;
  x0 += x1; x1 = rotl(x1,16); x1 ^= x0;
  x0 += x1; x1 = rotl(x1,24); x1 ^= x0;
  x0 += k1; x1 += k2 + 4u;
  x0 += x1; x1 = rotl(x1,13); x1 ^= x0;
  x0 += x1; x1 = rotl(x1,15); x1 ^= x0;
  x0 += x1; x1 = rotl(x1,26); x1 ^= x0;
  x0 += x1; x1 = rotl(x1, 6); x1 ^= x0;
  x0 += k2; x1 += k0 + 5u;
  o0 = x0; o1 = x1;
}

// Pre: w1eff[128][32] (cols 0..15 = W1[:, :16]; 16..31 folded perception pairs),
// w2t[128][16] = W2^T, c1[8][128] = b1 + W1[:,48:176].w[b].
__global__ __launch_bounds__(256) void nca_pre(
    const float* __restrict__ w, const float* __restrict__ W1,
    const float* __restrict__ b1, const float* __restrict__ W2,
    float* __restrict__ w1eff, float* __restrict__ w2t, float* __restrict__ c1)
{
  const int b = blockIdx.x, t = threadIdx.x;
  if (b == 0){
    for (int idx = t; idx < HIDN*32; idx += 256){
      int n = idx >> 5, k = idx & 31;
      float v;
      if (k < 16) v = W1[n*176 + k];
      else { int cc = k - 16; v = W1[n*176 + 16 + 2*cc] + W1[n*176 + 17 + 2*cc]; }
      w1eff[idx] = v;
    }
    for (int idx = t; idx < HIDN*CHN; idx += 256){
      int n = idx >> 4, cc = idx & 15;
      w2t[idx] = W2[cc*HIDN + n];
    }
  }
  if (t < HIDN){
    float s = b1[t];
    const float* wrow = W1 + t*176 + 48;
    const float* wb = w + b*WD;
    #pragma unroll 8
    for (int k = 0; k < WD; ++k) s = fmaf(wrow[k], wb[k], s);
    c1[b*HIDN + t] = s;
  }
}

// One NCA step. Block = 16x4 pixel tile x 4 hidden quarters (256 thr, q=wave).
// FIRST: X = input x. Else: X = Yp * (Mp & living(Yp alpha)) built in LDS.
template<bool FIRST>
__global__ __launch_bounds__(256, 6) void nca_step(
    const float* __restrict__ Xin,          // x if FIRST, else Y_{s-1}
    const unsigned char* __restrict__ Mp,   // M_{s-1} (ignored if FIRST)
    const float* __restrict__ w1eff, const float* __restrict__ w2t,
    const float* __restrict__ c1,
    uint32_t key0, uint32_t key1,
    float* __restrict__ Yn, unsigned char* __restrict__ Mn)
{
  __shared__ float xs[CHN][HW_][WW_];   //  6912 B: X tile + halo 1
  __shared__ float ya[TH+4][TW+4];      //   640 B: Y alpha + halo 2 (8x20)
  __shared__ float lifes[HW_][WW_];     //   432 B
  __shared__ float red[4][CHN][64];     // 16384 B: reduction, lane=px -> 2-way (free)

  const int T = blockIdx.x;
  const int b = T & 7;                  // image == XCD (%8 round-robin heuristic)
  const int t = T >> 3;
  const int tw0 = (t % TILES_X)*TW, th0 = (t / TILES_X)*TH;
  const int tid = threadIdx.x;

  // ---- staging: single global read of Y; X held in regs while life computes
  float xreg[7];
  if (!FIRST){
    // Y alpha with halo 2 (zero-pad OOB: 0 <= 0.1 never flips the mask)
    if (tid < (TH+4)*(TW+4)){
      int hh = tid / (TW+4), ww = tid % (TW+4);
      int g2 = th0 - 2 + hh, w2 = tw0 - 2 + ww;
      float v = 0.f;
      if ((unsigned)g2 < NH && (unsigned)w2 < NW)
        v = Xin[((b*CHN + 3)*NH + g2)*NW + w2];
      ya[hh][ww] = v;
    }
  }
  #pragma unroll
  for (int i = 0; i < 7; ++i){
    int idx = tid + i*256;
    float v = 0.f;
    if (idx < XS_N){
      int ch = idx / (HW_*WW_), rem = idx % (HW_*WW_);
      int hh = rem / WW_, ww = rem % WW_;
      int g2 = th0 - 1 + hh, w2 = tw0 - 1 + ww;
      if ((unsigned)g2 < NH && (unsigned)w2 < NW)
        v = Xin[((b*CHN + ch)*NH + g2)*NW + w2];
    }
    xreg[i] = v;
  }
  if (FIRST){
    #pragma unroll
    for (int i = 0; i < 7; ++i){
      int idx = tid + i*256;
      if (idx < XS_N){
        int rem = idx % (HW_*WW_);
        xs[idx / (HW_*WW_)][rem / WW_][rem % WW_] = xreg[i];
      }
    }
  } else {
    __syncthreads();                    // ya visible
    if (tid < HW_*WW_){                 // life over tile + halo 1 (108 elems)
      int hh = tid / WW_, ww = tid % WW_;
      int g2 = th0 - 1 + hh, w2 = tw0 - 1 + ww;
      float lf = 0.f;
      if ((unsigned)g2 < NH && (unsigned)w2 < NW){
        float mx = ya[hh][ww];
        #pragma unroll
        for (int dr = 0; dr < 3; ++dr)
          #pragma unroll
          for (int dc = 0; dc < 3; ++dc)
            mx = fmaxf(mx, ya[hh+dr][ww+dc]);
        lf = (Mp[b*PLANE + g2*NW + w2] && (mx > 0.1f)) ? 1.f : 0.f;
      }
      lifes[hh][ww] = lf;
    }
    __syncthreads();                    // lifes visible
    #pragma unroll
    for (int i = 0; i < 7; ++i){
      int idx = tid + i*256;
      if (idx < XS_N){
        int ch = idx / (HW_*WW_), rem = idx % (HW_*WW_);
        int hh = rem / WW_, ww = rem % WW_;
        xs[ch][hh][ww] = xreg[i] * lifes[hh][ww];
      }
    }
  }
  __syncthreads();

  const int px = tid & 63;          // pixel in 16x4 tile
  const int q  = tid >> 6;          // hidden quarter == wave id (0..3)
  const int c = px & 15, r = px >> 4;
  const int gh = th0 + r, gw = tw0 + c;
  const int pos = b*PLANE + gh*NW + gw;

  float xc[CHN], pc[CHN];
  #pragma unroll
  for (int ch = 0; ch < CHN; ++ch) xc[ch] = xs[ch][r+1][c+1];
  // grouped conv: out ch 0..7 -> sx, 8..15 -> sy (cross-correlation)
  #pragma unroll
  for (int ch = 0; ch < 8; ++ch){
    pc[ch] =      (xs[ch][r  ][c+2] - xs[ch][r  ][c  ])
           + 2.f*(xs[ch][r+1][c+2] - xs[ch][r+1][c  ])
           +     (xs[ch][r+2][c+2] - xs[ch][r+2][c  ]);
  }
  #pragma unroll
  for (int ch = 8; ch < 16; ++ch){
    pc[ch] =      (xs[ch][r+2][c  ] - xs[ch][r  ][c  ])
           + 2.f*(xs[ch][r+2][c+1] - xs[ch][r  ][c+1])
           +     (xs[ch][r+2][c+2] - xs[ch][r  ][c+2]);
  }

  float acc[CHN];
  #pragma unroll
  for (int i = 0; i < CHN; ++i) acc[i] = 0.f;
  // q is wave-uniform; readfirstlane keeps weight addresses provably scalar
  // (s_load path; SGPR=112 in green R5/R6 kernels).
  const int nbase = __builtin_amdgcn_readfirstlane(q) << 5;
  const float* c1b = c1 + b*HIDN;

  #pragma unroll 4
  for (int nn = 0; nn < 32; ++nn){
    const int n = nbase + nn;
    const float* wr = w1eff + (n << 5);
    float h0 = c1b[n], h1 = 0.f, h2 = 0.f, h3 = 0.f;
    #pragma unroll
    for (int k = 0; k < 8; ++k){
      h0 = fmaf(xc[k],   wr[k],    h0);
      h1 = fmaf(xc[k+8], wr[k+8],  h1);
      h2 = fmaf(pc[k],   wr[k+16], h2);
      h3 = fmaf(pc[k+8], wr[k+24], h3);
    }
    float hv = fmaxf((h0+h1)+(h2+h3), 0.f);
    const float* w2r = w2t + (n << 4);
    #pragma unroll
    for (int cc = 0; cc < CHN; ++cc) acc[cc] = fmaf(hv, w2r[cc], acc[cc]);
  }

  #pragma unroll
  for (int cc = 0; cc < CHN; ++cc) red[q][cc][px] = acc[cc];
  __syncthreads();

  // epilogue balanced across quarters: quarter q handles channels 4q..4q+3
  uint32_t o0, o1;
  threefry2x32(key0, key1, 0u, (uint32_t)pos, o0, o1);
  float uf = ((((o0 ^ o1) >> 31) == 0u) && (xc[3] > 0.1f)) ? 1.f : 0.f;
  #pragma unroll
  for (int cc = 0; cc < 4; ++cc){
    int ch = (q << 2) + cc;
    float v = ((red[0][ch][px] + red[1][ch][px]) +
               (red[2][ch][px] + red[3][ch][px]));
    Yn[((b*CHN + ch)*NH + gh)*NW + gw] = fmaf(v, uf, xc[ch]);
  }
  if (q == 0){  // wave-uniform branch; pre_life from (masked) X alpha
    float mx = xs[3][r][c];
    #pragma unroll
    for (int dr = 0; dr < 3; ++dr)
      #pragma unroll
      for (int dc = 0; dc < 3; ++dc)
        mx = fmaxf(mx, xs[3][r+dr][c+dc]);
    Mn[pos] = (mx > 0.1f) ? (unsigned char)1 : (unsigned char)0;
  }
}

// Final: out = Y_63 * (M_63 & living(Y_63 alpha))
__global__ __launch_bounds__(256) void nca_final(
    const float* __restrict__ Yp, const unsigned char* __restrict__ Mp,
    float* __restrict__ out)
{
  __shared__ float ya[TH+4][TW+4];     // 8x20
  __shared__ float lifes[TH][TW];
  const int T = blockIdx.x;
  const int b = T & 7;
  const int t = T >> 3;
  const int tw0 = (t % TILES_X)*TW, th0 = (t / TILES_X)*TH;
  const int tid = threadIdx.x;
  if (tid < (TH+4)*(TW+4)){
    int hh = tid / (TW+4), ww = tid % (TW+4);
    int g2 = th0 - 2 + hh, w2 = tw0 - 2 + ww;
    float v = 0.f;
    if ((unsigned)g2 < NH && (unsigned)w2 < NW)
      v = Yp[((b*CHN + 3)*NH + g2)*NW + w2];
    ya[hh][ww] = v;
  }
  __syncthreads();
  if (tid < TH*TW){
    int i = tid >> 4, j = tid & 15;
    float mx = ya[i+2][j+2];
    #pragma unroll
    for (int dr = 0; dr < 3; ++dr)
      #pragma unroll
      for (int dc = 0; dc < 3; ++dc)
        mx = fmaxf(mx, ya[i+1+dr][j+1+dc]);
    lifes[i][j] = (Mp[b*PLANE + (th0+i)*NW + (tw0+j)] && (mx > 0.1f)) ? 1.f : 0.f;
  }
  __syncthreads();
  for (int idx = tid; idx < CHN*TH*TW; idx += 256){
    int ch = idx >> 6, p = idx & 63;
    int i = p >> 4, j = p & 15;
    int o = ((b*CHN + ch)*NH + th0 + i)*NW + tw0 + j;
    out[o] = Yp[o] * lifes[i][j];
  }
}

extern "C" void kernel_launch(void* const* d_in, const int* in_sizes, int n_in,
                              void* d_out, int out_size, void* d_ws, size_t ws_size,
                              hipStream_t stream) {
  const float* x  = (const float*)d_in[0];
  const float* w  = (const float*)d_in[1];
  // d_in[2] = sobel (hard-coded), d_in[6] = steps (=64, hard-coded)
  const float* W1 = (const float*)d_in[3];
  const float* b1 = (const float*)d_in[4];
  const float* W2 = (const float*)d_in[5];
  float* out = (float*)d_out;
  char* ws = (char*)d_ws;

  size_t off = 0;
  float*    w1eff = (float*)(ws + off);    off += (size_t)HIDN*32*4;
  float*    w2t   = (float*)(ws + off);    off += (size_t)HIDN*CHN*4;
  float*    c1    = (float*)(ws + off);    off += (size_t)NB*HIDN*4;
  float*    Yb0   = (float*)(ws + off);    off += (size_t)NB*CHN*PLANE*4;
  float*    Yb1   = (float*)(ws + off);    off += (size_t)NB*CHN*PLANE*4;
  unsigned char* Mb0 = (unsigned char*)(ws + off); off += (size_t)NB*PLANE;
  unsigned char* Mb1 = (unsigned char*)(ws + off); off += (size_t)NB*PLANE;
  (void)ws_size; (void)in_sizes; (void)n_in; (void)out_size;

  // step keys are input-independent constants: compute on host, pass as args
  uint32_t k0[NSTEPS], k1[NSTEPS];
  for (int s = 0; s < NSTEPS; ++s) threefry2x32(0u, 42u, 0u, (uint32_t)s, k0[s], k1[s]);

  nca_pre<<<dim3(NB), dim3(256), 0, stream>>>(w, W1, b1, W2, w1eff, w2t, c1);

  nca_step<true><<<dim3(NBLK), dim3(256), 0, stream>>>(
      x, Mb1 /*unused*/, w1eff, w2t, c1, k0[0], k1[0], Yb0, Mb0);
  for (int s = 1; s < NSTEPS; ++s){
    const float* Yp = (s & 1) ? Yb0 : Yb1;
    float*       Yn = (s & 1) ? Yb1 : Yb0;
    const unsigned char* Mq = (s & 1) ? Mb0 : Mb1;
    unsigned char*       Mn = (s & 1) ? Mb1 : Mb0;
    nca_step<false><<<dim3(NBLK), dim3(256), 0, stream>>>(
        Yp, Mq, w1eff, w2t, c1, k0[s], k1[s], Yn, Mn);
  }
  // s=63 (odd) wrote Yb1/Mb1
  nca_final<<<dim3(NBLK), dim3(256), 0, stream>>>(Yb1, Mb1, out);
}